// Round 5
// baseline (63.284 us; speedup 1.0000x reference)
//
#include <hip/hip_runtime.h>

#define NN 4096
#define DD 512
#define CC 1000
#define NB 64   // 64 row/col panels of 64 -> triangle = 64*65/2 = 2080 wave-tiles

typedef __attribute__((ext_vector_type(8))) __bf16 bf16x8;
typedef __attribute__((ext_vector_type(4))) float f32x4;

__device__ __forceinline__ unsigned short f2bf(float f) {
  unsigned int u = __float_as_uint(f);
  u += 0x7fffu + ((u >> 16) & 1u);   // round-to-nearest-even (no NaN in this data)
  return (unsigned short)(u >> 16);
}

// ---------------- kernel 1: normalize rows -> bf16 X, init out --------------
__global__ __launch_bounds__(256) void knorm(const float* __restrict__ embs,
                                             unsigned short* __restrict__ Xb,
                                             float* __restrict__ out) {
  int tid = threadIdx.x;
  if (blockIdx.x == 0 && tid == 0) out[0] = 0.f;  // stream-ordered before kmain
  int lane = tid & 63;
  int row = blockIdx.x * 4 + (tid >> 6);
  const float* rp = embs + (size_t)row * DD;
  float4 v0 = ((const float4*)rp)[lane * 2];
  float4 v1 = ((const float4*)rp)[lane * 2 + 1];
  float ss = v0.x * v0.x + v0.y * v0.y + v0.z * v0.z + v0.w * v0.w +
             v1.x * v1.x + v1.y * v1.y + v1.z * v1.z + v1.w * v1.w;
  for (int off = 32; off; off >>= 1) ss += __shfl_xor(ss, off);
  float scale = 1.0f / fmaxf(sqrtf(ss), 1e-8f);
  float f[8] = {v0.x, v0.y, v0.z, v0.w, v1.x, v1.y, v1.z, v1.w};
  unsigned int h[8];
#pragma unroll
  for (int i = 0; i < 8; ++i) h[i] = f2bf(f[i] * scale);
  uint4 o;
  o.x = h[0] | (h[1] << 16);
  o.y = h[2] | (h[3] << 16);
  o.z = h[4] | (h[5] << 16);
  o.w = h[6] | (h[7] << 16);
  *(uint4*)(Xb + (size_t)row * DD + lane * 8) = o;
}

// ---------------- kernel 2: barrier-free per-wave GEMM tiles ----------------
// Each WAVE independently computes one 64x64 triangle tile of sim = X X^T,
// reading MFMA fragments DIRECTLY from global (X is 4MB, L2-resident):
// no LDS, no __syncthreads, no vmcnt(0) drains -- pure register dataflow the
// compiler software-pipelines with counted vmcnt. Fragment addresses are
// loop-invariant bases + ks*64B immediate offsets (fold into the load).
// Per-element triangle rule: col>row -> emit both ordered terms (Aij gather +
// transposed gather); col==row -> single term (in-MFMA diagonal, proven
// error ~7e-8 << 5.8e-7 threshold); col<row skipped.
__global__ __launch_bounds__(256) void kmain(const unsigned short* __restrict__ Xb,
                                             const int* __restrict__ labels,
                                             const float* __restrict__ Aij,
                                             float* __restrict__ out) {
  int lane = threadIdx.x & 63;
  int wid = blockIdx.x * 4 + (threadIdx.x >> 6);

  // decode triangular tile index: by = row-panel, bx in [by, NB)
  int t = wid;
  int by = 0;
  while (t >= (NB - by)) { t -= (NB - by); ++by; }
  int bx = by + t;
  int row0 = by * 64;
  int col0 = bx * 64;

  // loop-invariant fragment base addresses (16x16x32 layout, proven R1-R4):
  // A frag m: row = row0 + m*16 + (lane&15), k-chunk byte = (lane>>4)*16
  const char* baseA[4];
  const char* baseB[4];
#pragma unroll
  for (int m = 0; m < 4; ++m) {
    baseA[m] = (const char*)(Xb + (size_t)(row0 + m * 16 + (lane & 15)) * DD) +
               (lane >> 4) * 16;
    baseB[m] = (const char*)(Xb + (size_t)(col0 + m * 16 + (lane & 15)) * DD) +
               (lane >> 4) * 16;
  }

  f32x4 acc[4][4];
#pragma unroll
  for (int m = 0; m < 4; ++m)
#pragma unroll
    for (int n = 0; n < 4; ++n) acc[m][n] = (f32x4){0.f, 0.f, 0.f, 0.f};

#pragma unroll
  for (int ks = 0; ks < DD / 32; ++ks) {  // 16 k-steps of 32
    bf16x8 a[4], b[4];
#pragma unroll
    for (int m = 0; m < 4; ++m) a[m] = *(const bf16x8*)(baseA[m] + ks * 64);
#pragma unroll
    for (int n = 0; n < 4; ++n) b[n] = *(const bf16x8*)(baseB[n] + ks * 64);
#pragma unroll
    for (int m = 0; m < 4; ++m)
#pragma unroll
      for (int n = 0; n < 4; ++n)
        acc[m][n] = __builtin_amdgcn_mfma_f32_16x16x32_bf16(a[m], b[n], acc[m][n], 0, 0, 0);
  }

  // fused epilogue: gate on d_emb first (rarely true off-diagonal) so gathers
  // stay behind an exec-masked branch; per-element triangle/mirror rule.
  float lsum = 0.f;
#pragma unroll
  for (int m = 0; m < 4; ++m) {
#pragma unroll
    for (int n = 0; n < 4; ++n) {
#pragma unroll
      for (int j = 0; j < 4; ++j) {
        float s = acc[m][n][j];
        float de = 1.0f - s;
        if (de < 0.7f) {
          int row = row0 + m * 16 + ((lane >> 4) * 4 + j);
          int col = col0 + n * 16 + (lane & 15);
          if (col >= row) {
            int lr = labels[row], lc = labels[col];
            float dc = Aij[lr * CC + lc];
            if (dc < 0.7f) {
              float d = de - dc;
              lsum += d * d;
            }
            if (col > row) {  // mirrored ordered pair (col,row)
              float dc2 = Aij[lc * CC + lr];
              if (dc2 < 0.7f) {
                float d = de - dc2;
                lsum += d * d;
              }
            }
          }
        }
      }
    }
  }
  // per-wave reduce + single atomic (waves are fully independent; almost all
  // waves have lsum==0 -> no atomic traffic except diagonal tiles)
  for (int off = 32; off; off >>= 1) lsum += __shfl_xor(lsum, off);
  if (lane == 0) {
    float v = lsum * (1.0f / ((float)NN * (float)NN));
    if (v != 0.f) atomicAdd(out, v);
  }
}

extern "C" void kernel_launch(void* const* d_in, const int* in_sizes, int n_in,
                              void* d_out, int out_size, void* d_ws, size_t ws_size,
                              hipStream_t stream) {
  const float* embs = (const float*)d_in[0];
  const int* labels = (const int*)d_in[1];
  const float* Aij = (const float*)d_in[2];
  float* out = (float*)d_out;
  unsigned short* Xb = (unsigned short*)d_ws;  // 4096*512 bf16 = 4 MB

  knorm<<<NN / 4, 256, 0, stream>>>(embs, Xb, out);  // fills Xb, zeroes out
  int nwaves = (NB * (NB + 1)) / 2;                  // 2080 wave-tiles
  kmain<<<nwaves / 4, 256, 0, stream>>>(Xb, labels, Aij, out);
}

// Round 6
// 39.549 us; speedup vs baseline: 1.6001x; 1.6001x over previous
//
#include <hip/hip_runtime.h>

#define NN 4096
#define DD 512
#define CC 1000
#define NB 64        // 64 row/col panels of 64 -> triangle = 64*65/2 = 2080 wave-tiles
#define KT (DD / 32) // 16 k-tiles of 32

typedef __attribute__((ext_vector_type(8))) __bf16 bf16x8;
typedef __attribute__((ext_vector_type(4))) float f32x4;

__device__ __forceinline__ unsigned short f2bf(float f) {
  unsigned int u = __float_as_uint(f);
  u += 0x7fffu + ((u >> 16) & 1u);   // round-to-nearest-even (no NaN in this data)
  return (unsigned short)(u >> 16);
}

// ---------------- kernel 1: normalize rows -> PACKED bf16 fragments ---------
// Packed layout: Xp is an array of 1KB fragment-tiles, one per (row-tile p,
// k-tile ks). Within a tile, 16B unit l holds X[p*16 + (l&15)][ks*32 +
// (l>>4)*8 .. +8] -- exactly the mfma_f32_16x16x32_bf16 A/B fragment for
// lane l. kmain's fragment load is then ONE contiguous, 1KB-aligned
// global_load_dwordx4 per wave (R5's 16-line scatter is gone).
__global__ __launch_bounds__(256) void knorm(const float* __restrict__ embs,
                                             uint4* __restrict__ Xp,
                                             float* __restrict__ out) {
  int tid = threadIdx.x;
  if (blockIdx.x == 0 && tid == 0) out[0] = 0.f;  // stream-ordered before kmain
  int lane = tid & 63;
  int row = blockIdx.x * 4 + (tid >> 6);
  const float* rp = embs + (size_t)row * DD;
  float4 v0 = ((const float4*)rp)[lane * 2];
  float4 v1 = ((const float4*)rp)[lane * 2 + 1];
  float ss = v0.x * v0.x + v0.y * v0.y + v0.z * v0.z + v0.w * v0.w +
             v1.x * v1.x + v1.y * v1.y + v1.z * v1.z + v1.w * v1.w;
  for (int off = 32; off; off >>= 1) ss += __shfl_xor(ss, off);
  float scale = 1.0f / fmaxf(sqrtf(ss), 1e-8f);
  float f[8] = {v0.x, v0.y, v0.z, v0.w, v1.x, v1.y, v1.z, v1.w};
  unsigned int h[8];
#pragma unroll
  for (int i = 0; i < 8; ++i) h[i] = f2bf(f[i] * scale);
  uint4 o;
  o.x = h[0] | (h[1] << 16);
  o.y = h[2] | (h[3] << 16);
  o.z = h[4] | (h[5] << 16);
  o.w = h[6] | (h[7] << 16);
  // this lane holds elements [lane*8, lane*8+8) of row -> k-tile ks = lane>>2,
  // k-sub = lane&3; packed 16B-unit index:
  int p = row >> 4;
  int ks = lane >> 2;
  int idx16 = (p * KT + ks) * 64 + ((lane & 3) << 4) + (row & 15);
  Xp[idx16] = o;
}

// ---------------- kernel 2: barrier-free per-wave GEMM, packed frags --------
// Each WAVE independently computes one 64x64 triangle tile of sim = X X^T.
// Fragment loads are contiguous 1KB reads from the packed layout (L2-
// resident, 4MB); explicit 3-stage register pipeline (fully unrolled ->
// static indices, no scratch) keeps 16 loads in flight so the compiler's
// counted vmcnt waits + 2 waves/SIMD hide the ~250cy L2 latency.
// No LDS, no barriers. Per-element triangle rule: col>row -> emit both
// ordered terms; col==row -> single term (in-MFMA diagonal, error ~7e-8).
__global__ __launch_bounds__(256, 2) void kmain(const uint4* __restrict__ Xp,
                                                const int* __restrict__ labels,
                                                const float* __restrict__ Aij,
                                                float* __restrict__ out) {
  int lane = threadIdx.x & 63;
  int wid = blockIdx.x * 4 + (threadIdx.x >> 6);

  // decode triangular tile index: by = row-panel, bx in [by, NB)
  int t = wid;
  int by = 0;
  while (t >= (NB - by)) { t -= (NB - by); ++by; }
  int bx = by + t;
  int row0 = by * 64;
  int col0 = bx * 64;

  // per-row-tile base pointers (16B units); frag for k-tile ks at +ks*64
  const uint4* pa[4];
  const uint4* pb[4];
#pragma unroll
  for (int m = 0; m < 4; ++m) {
    pa[m] = Xp + (size_t)(by * 4 + m) * (KT * 64) + lane;
    pb[m] = Xp + (size_t)(bx * 4 + m) * (KT * 64) + lane;
  }

  f32x4 acc[4][4];
#pragma unroll
  for (int m = 0; m < 4; ++m)
#pragma unroll
    for (int n = 0; n < 4; ++n) acc[m][n] = (f32x4){0.f, 0.f, 0.f, 0.f};

  bf16x8 a[3][4], b[3][4];  // 3-stage pipeline (statically indexed via unroll)
#pragma unroll
  for (int s = 0; s < 2; ++s) {
#pragma unroll
    for (int m = 0; m < 4; ++m) {
      a[s][m] = *(const bf16x8*)(pa[m] + s * 64);
      b[s][m] = *(const bf16x8*)(pb[m] + s * 64);
    }
  }
#pragma unroll
  for (int ks = 0; ks < KT; ++ks) {
    const int cur = ks % 3;
    const int nxt = (ks + 2) % 3;
    if (ks + 2 < KT) {
#pragma unroll
      for (int m = 0; m < 4; ++m) {
        a[nxt][m] = *(const bf16x8*)(pa[m] + (ks + 2) * 64);
        b[nxt][m] = *(const bf16x8*)(pb[m] + (ks + 2) * 64);
      }
    }
#pragma unroll
    for (int m = 0; m < 4; ++m)
#pragma unroll
      for (int n = 0; n < 4; ++n)
        acc[m][n] = __builtin_amdgcn_mfma_f32_16x16x32_bf16(a[cur][m], b[cur][n],
                                                            acc[m][n], 0, 0, 0);
  }

  // fused epilogue: gate on d_emb first (rarely true off-diagonal) so gathers
  // stay behind an exec-masked branch; per-element triangle/mirror rule.
  float lsum = 0.f;
#pragma unroll
  for (int m = 0; m < 4; ++m) {
#pragma unroll
    for (int n = 0; n < 4; ++n) {
#pragma unroll
      for (int j = 0; j < 4; ++j) {
        float s = acc[m][n][j];
        float de = 1.0f - s;
        if (de < 0.7f) {
          int row = row0 + m * 16 + ((lane >> 4) * 4 + j);
          int col = col0 + n * 16 + (lane & 15);
          if (col >= row) {
            int lr = labels[row], lc = labels[col];
            float dc = Aij[lr * CC + lc];
            if (dc < 0.7f) {
              float d = de - dc;
              lsum += d * d;
            }
            if (col > row) {  // mirrored ordered pair (col,row)
              float dc2 = Aij[lc * CC + lr];
              if (dc2 < 0.7f) {
                float d = de - dc2;
                lsum += d * d;
              }
            }
          }
        }
      }
    }
  }
  // per-wave reduce + single atomic (almost all waves have lsum==0)
  for (int off = 32; off; off >>= 1) lsum += __shfl_xor(lsum, off);
  if (lane == 0) {
    float v = lsum * (1.0f / ((float)NN * (float)NN));
    if (v != 0.f) atomicAdd(out, v);
  }
}

extern "C" void kernel_launch(void* const* d_in, const int* in_sizes, int n_in,
                              void* d_out, int out_size, void* d_ws, size_t ws_size,
                              hipStream_t stream) {
  const float* embs = (const float*)d_in[0];
  const int* labels = (const int*)d_in[1];
  const float* Aij = (const float*)d_in[2];
  float* out = (float*)d_out;
  uint4* Xp = (uint4*)d_ws;  // packed fragment tiles: 4096*512 bf16 = 4 MB

  knorm<<<NN / 4, 256, 0, stream>>>(embs, Xp, out);  // fills Xp, zeroes out
  int nwaves = (NB * (NB + 1)) / 2;                  // 2080 wave-tiles
  kmain<<<nwaves / 4, 256, 0, stream>>>(Xp, labels, Aij, out);
}

// Round 7
// 24.160 us; speedup vs baseline: 2.6193x; 1.6369x over previous
//
#include <hip/hip_runtime.h>
#include <hip/hip_fp8.h>

#define NN 4096
#define DD 512
#define CC 1000
#define NB 64   // 64x64 tiles -> triangle grid 64*65/2 = 2080 blocks

typedef __attribute__((ext_vector_type(4))) float f32x4;

// ---------------- kernel 1: normalize rows -> fp8 e4m3 X, init out ---------
// one wave per row; fp32 sum-of-squares, shuffle reduce, scale, fp8 quantize.
// X shrinks to 2 MB: fits comfortably in every XCD's 4 MiB L2 (bf16's 4 MB
// exactly filled it -> capacity thrash), and halves L2->CU traffic in kmain.
__global__ __launch_bounds__(256) void knorm(const float* __restrict__ embs,
                                             unsigned char* __restrict__ Xq,
                                             float* __restrict__ out) {
  int tid = threadIdx.x;
  if (blockIdx.x == 0 && tid == 0) out[0] = 0.f;  // stream-ordered before kmain
  int lane = tid & 63;
  int row = blockIdx.x * 4 + (tid >> 6);
  const float* rp = embs + (size_t)row * DD;
  float4 v0 = ((const float4*)rp)[lane * 2];
  float4 v1 = ((const float4*)rp)[lane * 2 + 1];
  float ss = v0.x * v0.x + v0.y * v0.y + v0.z * v0.z + v0.w * v0.w +
             v1.x * v1.x + v1.y * v1.y + v1.z * v1.z + v1.w * v1.w;
  for (int off = 32; off; off >>= 1) ss += __shfl_xor(ss, off);
  float scale = 1.0f / fmaxf(sqrtf(ss), 1e-8f);
  float f[8] = {v0.x, v0.y, v0.z, v0.w, v1.x, v1.y, v1.z, v1.w};
  unsigned long long o = 0;
#pragma unroll
  for (int i = 0; i < 8; ++i) {
    __hip_fp8_e4m3 q(f[i] * scale);  // OCP e4m3fn, RNE
    o |= (unsigned long long)q.__x << (8 * i);
  }
  *(unsigned long long*)(Xq + (size_t)row * DD + lane * 8) = o;
}

// ---------------- kernel 2: triangular fused fp8 X @ X^T -> gated loss ------
// R4's proven structure verbatim (64x64 tiles, triangle grid ~8 blocks/CU,
// 2-barrier schedule, global_load_lds(16B) with both-sides XOR swizzle); only
// the dtype changed: BK=128 fp8 -> rows are again 128B so the staging/swizzle
// geometry is byte-identical to R4. MFMA = f32_16x16x32_fp8_fp8 (bf16 rate).
// ds_read is 8B/lane; swizzle makes it 2-way bank aliasing (free, m136).
// Per-element triangle rule: col>row -> both ordered terms (mirrored Aij
// gather); col==row -> single term (in-MFMA diagonal); col<row skipped.
__global__ __launch_bounds__(256) void kmain(const unsigned char* __restrict__ Xq,
                                             const int* __restrict__ labels,
                                             const float* __restrict__ Aij,
                                             float* __restrict__ out) {
  __shared__ __align__(16) unsigned char As[64 * 128];  // 64 rows x 128B (BK=128)
  __shared__ __align__(16) unsigned char Bs[64 * 128];
  int tid = threadIdx.x;
  int lane = tid & 63;
  int w = tid >> 6;
  int wr = w >> 1, wc = w & 1;

  // decode triangular block index: by = row-block, bx in [by, NB)
  int t = blockIdx.x;
  int by = 0;
  while (t >= (NB - by)) { t -= (NB - by); ++by; }
  int bx = by + t;
  int row0 = by * 64;
  int col0 = bx * 64;

  f32x4 acc[2][2];
#pragma unroll
  for (int m = 0; m < 2; ++m)
#pragma unroll
    for (int n = 0; n < 2; ++n) acc[m][n] = (f32x4){0.f, 0.f, 0.f, 0.f};

  for (int it = 0; it < DD / 128; ++it) {  // 4 K-steps of 128 fp8
    int k0 = it * 128;
    if (it) __syncthreads();
#pragma unroll
    for (int i = 0; i < 2; ++i) {
      int idx = i * 256 + tid;              // 16B chunk index (512 chunks = 8KB)
      int r = idx >> 3;                     // tile row (128B per row)
      int c = idx & 7;                      // 16B chunk within row
      int srcB = ((c ^ (r & 7)) << 4);      // inverse-swizzled source byte
      const unsigned char* ga = Xq + (size_t)(row0 + r) * DD + k0 + srcB;
      const unsigned char* gb = Xq + (size_t)(col0 + r) * DD + k0 + srcB;
      __builtin_amdgcn_global_load_lds(
          (const __attribute__((address_space(1))) void*)ga,
          (__attribute__((address_space(3))) void*)(As + idx * 16), 16, 0, 0);
      __builtin_amdgcn_global_load_lds(
          (const __attribute__((address_space(1))) void*)gb,
          (__attribute__((address_space(3))) void*)(Bs + idx * 16), 16, 0, 0);
    }
    __syncthreads();
#pragma unroll
    for (int ks = 0; ks < 4; ++ks) {        // 4 MFMA k-sub-steps of 32
      int q = (ks << 1) | (lane >> 5);      // 16B-chunk of this lane's 8B
      int o = ((lane >> 4) & 1) << 3;       // 8B half within chunk
      long a[2], b[2];
#pragma unroll
      for (int m = 0; m < 2; ++m) {
        int r = wr * 32 + m * 16 + (lane & 15);
        a[m] = *(const long*)(As + r * 128 + (((q ^ (r & 7)) << 4) | o));
      }
#pragma unroll
      for (int n = 0; n < 2; ++n) {
        int r = wc * 32 + n * 16 + (lane & 15);
        b[n] = *(const long*)(Bs + r * 128 + (((q ^ (r & 7)) << 4) | o));
      }
#pragma unroll
      for (int m = 0; m < 2; ++m)
#pragma unroll
        for (int n = 0; n < 2; ++n)
          acc[m][n] = __builtin_amdgcn_mfma_f32_16x16x32_fp8_fp8(a[m], b[n],
                                                                 acc[m][n], 0, 0, 0);
    }
  }

  // fused epilogue: gate on d_emb first (rarely true off-diagonal) so gathers
  // stay behind an exec-masked branch; per-element triangle/mirror rule.
  float lsum = 0.f;
#pragma unroll
  for (int m = 0; m < 2; ++m) {
#pragma unroll
    for (int n = 0; n < 2; ++n) {
#pragma unroll
      for (int j = 0; j < 4; ++j) {
        float s = acc[m][n][j];
        float de = 1.0f - s;
        if (de < 0.7f) {
          int row = row0 + wr * 32 + m * 16 + ((lane >> 4) * 4 + j);
          int col = col0 + wc * 32 + n * 16 + (lane & 15);
          if (col >= row) {
            int lr = labels[row], lc = labels[col];
            float dc = Aij[lr * CC + lc];
            if (dc < 0.7f) {
              float d = de - dc;
              lsum += d * d;
            }
            if (col > row) {  // mirrored ordered pair (col,row)
              float dc2 = Aij[lc * CC + lr];
              if (dc2 < 0.7f) {
                float d = de - dc2;
                lsum += d * d;
              }
            }
          }
        }
      }
    }
  }
  for (int off = 32; off; off >>= 1) lsum += __shfl_xor(lsum, off);
  __shared__ float red[4];
  if ((tid & 63) == 0) red[w] = lsum;
  __syncthreads();
  if (tid == 0) {
    float v = (red[0] + red[1] + red[2] + red[3]) * (1.0f / ((float)NN * (float)NN));
    if (v != 0.f) atomicAdd(out, v);
  }
}

extern "C" void kernel_launch(void* const* d_in, const int* in_sizes, int n_in,
                              void* d_out, int out_size, void* d_ws, size_t ws_size,
                              hipStream_t stream) {
  const float* embs = (const float*)d_in[0];
  const int* labels = (const int*)d_in[1];
  const float* Aij = (const float*)d_in[2];
  float* out = (float*)d_out;
  unsigned char* Xq = (unsigned char*)d_ws;  // 4096*512 fp8 = 2 MB

  knorm<<<NN / 4, 256, 0, stream>>>(embs, Xq, out);            // fills Xq, zeroes out
  kmain<<<(NB * (NB + 1)) / 2, 256, 0, stream>>>(Xq, labels, Aij, out);  // triangle
}